// Round 10
// baseline (154.484 us; speedup 1.0000x reference)
//
#include <hip/hip_runtime.h>
#include <math.h>

#define BB 16
#define SS 8192
#define HH 256
#define MM 16
#define DNC 64           // k_dft chunks: s-split of [0, 8192)
#define DL 128           // s-rows per chunk
#define SCH 16           // v per k_synth block
#define SNC 129          // k_synth chunks: 128 full + 1 edge
#define QOFF (BB * MM * 2 * HH)   // 131072: ABp h-half stride

// ws layout (floats): T [8192][32] at 0 (262144), ABp [2][BB][MM][2][HH] at
// 262144 (262144 floats).  Total 2 MB.
// d_out scratch: Xp [BB][DNC][MM][2][HH] (8.39M floats, 33.5 MB) at 0, Wt_r at
// 16M floats, Wt_i at 17M floats — all consumed before k_synth overwrites.

// Fused setup: blocks 0..511 build twiddle table T[s][2k]=cos(2pi k s/SS),
// [2k+1]=sin (full s<8192); blocks 512..1023 transpose W
// (Wt[m][h][k'] = w[h][k'][m]) via padded LDS.
__global__ __launch_bounds__(256) void k_pre(const float* __restrict__ wr,
                                             const float* __restrict__ wi,
                                             float* __restrict__ T,
                                             float* __restrict__ Wtr,
                                             float* __restrict__ Wti) {
    const int t = threadIdx.x;
    if (blockIdx.x < 512) {
        int idx = blockIdx.x * 256 + t;     // 0 .. 131071
        int s = idx >> 4, k = idx & 15;
        int r = (k * s) & (SS - 1);         // exact angle reduction
        float th = (float)r * (6.28318530717958647692f / (float)SS);
        float sn, cn;
        sincosf(th, &sn, &cn);
        T[s * 32 + 2 * k]     = cn;
        T[s * 32 + 2 * k + 1] = sn;
    } else {
        __shared__ float lds[4096 + 256];
        int bid = blockIdx.x - 512;         // 0..511
        int h = bid & 255, y = bid >> 8;
        const float* src = (y == 0 ? wr : wi) + (size_t)h * 4096;
        float* dst = (y == 0 ? Wtr : Wti);
#pragma unroll
        for (int j = 0; j < 16; j++) {
            int i = j * 256 + t;
            lds[i + (i >> 4)] = src[i];
        }
        __syncthreads();
#pragma unroll
        for (int m = 0; m < 16; m++) {
            int i = t * 16 + m;
            dst[(size_t)m * (HH * HH) + (size_t)h * HH + t] = lds[i + (i >> 4)];
        }
    }
}

// Branchless exact-GELU via A&S 7.1.26 erf (|err| ~ 1.5e-7).
__device__ __forceinline__ float fast_gelu(float y) {
    float x  = fabsf(y) * 0.70710678118654752f;
    float t  = __builtin_amdgcn_rcpf(fmaf(0.3275911f, x, 1.0f));
    float e  = __expf(-x * x);
    float p  = fmaf(fmaf(fmaf(fmaf(1.061405429f, t, -1.453152027f), t,
                   1.421413741f), t, -0.284496736f), t, 0.254829592f) * t;
    float erfabs = fmaf(-p, e, 1.0f);
    return fmaf(0.5f * fabsf(y), erfabs, 0.5f * y);
}

// Stage 1: pruned forward DFT, UNFOLDED, single contiguous read stream per
// block (R2's proven 52us structure), with the block's 128-row twiddle strip
// (16 KB) staged to LDS once.  Inner loop: 1 scalar x load (1 KB/block-row,
// one sequential stream) + 8 uniform-address ds_read_b128 (broadcast,
// conflict-free) + 32 FMA.  VALU-bound by design.
// cs[k] = sum_s x*cos(2pi k s/S), sn[k] = sum_s x*sin;  X = cs - i*sn.
__global__ __launch_bounds__(256) void k_dft(const float* __restrict__ x,
                                             const float* __restrict__ T,
                                             float* __restrict__ Xp) {
    const int c = blockIdx.x, b = blockIdx.y, t = threadIdx.x;
    const int s0 = c * DL;

    __shared__ float tws[DL * 32];               // 16 KB
    {
        const float4* src = (const float4*)(T + (size_t)s0 * 32);
        float4* dst = (float4*)tws;
#pragma unroll
        for (int j = 0; j < 4; j++)              // 4096 floats, coalesced
            dst[j * 256 + t] = src[j * 256 + t];
    }
    __syncthreads();

    float cs[MM], sn[MM];
#pragma unroll
    for (int k = 0; k < MM; k++) { cs[k] = 0.f; sn[k] = 0.f; }

    const float* xp = x + ((size_t)b * SS + s0) * HH + t;

#pragma unroll 8
    for (int i = 0; i < DL; i++) {
        float xv = xp[(size_t)i * HH];
        const float4* tw4 = (const float4*)(tws + i * 32);  // uniform addr
#pragma unroll
        for (int j = 0; j < 8; j++) {
            float4 tt = tw4[j];
            cs[2 * j]     = fmaf(tt.x, xv, cs[2 * j]);
            sn[2 * j]     = fmaf(tt.y, xv, sn[2 * j]);
            cs[2 * j + 1] = fmaf(tt.z, xv, cs[2 * j + 1]);
            sn[2 * j + 1] = fmaf(tt.w, xv, sn[2 * j + 1]);
        }
    }

    size_t base = ((size_t)(b * DNC + c) * MM) * (2 * HH) + t;
#pragma unroll
    for (int k = 0; k < MM; k++) {
        Xp[base + (size_t)k * (2 * HH)]      = cs[k];
        Xp[base + (size_t)k * (2 * HH) + HH] = sn[k];
    }
}

// Stage 2 (fused reduce+mix, h-split by 2): block (m, b, q) handles h-half
// [q*128, q*128+128).  Phase A: sum Xp over 64 partials (two p-halves across
// thread groups, LDS-combined).  Phase B: partial O[k'] over this h-half:
// X = cs - i*sn;  O[k'] = sum_h X[h]*(wr+i*wi)[h,k',m];
// ABp[q] = scale*Re(O), ABp[q]+HH = -scale*Im(O); k_synth sums the 2 halves.
__global__ __launch_bounds__(256) void k_mix(const float* __restrict__ Xp,
                                             const float* __restrict__ Wtr,
                                             const float* __restrict__ Wti,
                                             float* __restrict__ ABp) {
    const int m = blockIdx.x, b = blockIdx.y, q = blockIdx.z, t = threadIdx.x;
    const int h0 = q * 128;
    __shared__ float tmp[2][2][128];
    __shared__ float xr_s[128], xs_s[128];

    {   // phase A: hh = t&127, p-half = t>>7 (32 p's each)
        int hh = t & 127, ph = t >> 7;
        float s0 = 0.f, s1 = 0.f;
        size_t base = (((size_t)b * DNC + ph * 32) * MM + m) * (2 * HH) + h0 + hh;
        const size_t ps = (size_t)MM * 2 * HH;
#pragma unroll 4
        for (int p = 0; p < 32; p++) {
            s0 += Xp[base + (size_t)p * ps];
            s1 += Xp[base + (size_t)p * ps + HH];
        }
        tmp[ph][0][hh] = s0;
        tmp[ph][1][hh] = s1;
        __syncthreads();
        if (t < 128) {
            xr_s[t] = tmp[0][0][t] + tmp[1][0][t];
            xs_s[t] = tmp[0][1][t] + tmp[1][1][t];
        }
        __syncthreads();
    }

    // phase B: t = k', loop over this h-half
    const float* wr_m = Wtr + (size_t)m * (HH * HH) + (size_t)h0 * HH;
    const float* wi_m = Wti + (size_t)m * (HH * HH) + (size_t)h0 * HH;
    float re = 0.f, im = 0.f;
#pragma unroll 8
    for (int hh = 0; hh < 128; hh++) {
        float a  = wr_m[(size_t)hh * HH + t];   // lane-contiguous, 1KB/wave
        float bw = wi_m[(size_t)hh * HH + t];
        float xr = xr_s[hh];                    // LDS broadcast
        float xs = xs_s[hh];
        re = fmaf(xr, a, re);  re = fmaf(xs, bw, re);
        im = fmaf(xr, bw, im); im = fmaf(-xs, a, im);
    }
    float scale = (m == 0 ? 1.f : 2.f) / (float)SS;
    size_t o = (size_t)q * QOFF + (((size_t)b * MM + m) * 2) * HH + t;
    ABp[o]      = scale * re;
    ABp[o + HH] = -scale * im;
}

// Stage 3: folded synthesis + GELU.  4 outputs per table row:
// y[v]=Pp+Qp, y[4096-v]=Pm-Qm, y[4096+v]=Pm+Qm, y[8192-v]=Pp-Qp
__global__ __launch_bounds__(256) void k_synth(const float* __restrict__ ABp,
                                               const float* __restrict__ T,
                                               float* __restrict__ out) {
    const int c = blockIdx.x, b = blockIdx.y, h = threadIdx.x;
    float a[MM], bc[MM];
#pragma unroll
    for (int k = 0; k < MM; k++) {
        size_t o = (((size_t)b * MM + k) * 2) * HH + h;
        a[k]  = ABp[o]      + ABp[o + QOFF];
        bc[k] = ABp[o + HH] + ABp[o + HH + QOFF];
    }
    const int nv = (c == SNC - 1) ? 1 : SCH;
    const int v0 = c * SCH;
    float* ob = out + (size_t)b * SS * HH + h;

#pragma unroll 2
    for (int i = 0; i < nv; i++) {
        int v = v0 + i;
        const float4* tw4 = (const float4*)(T + (size_t)v * 32);
        float Pe = 0.f, Po = 0.f, Qe = 0.f, Qo = 0.f;
#pragma unroll
        for (int j = 0; j < 8; j++) {
            float t4x, t4y, t4z, t4w;
            float4 t = tw4[j];
            t4x = t.x; t4y = t.y; t4z = t.z; t4w = t.w;
            Pe = fmaf(a[2 * j],      t4x, Pe);
            Qe = fmaf(bc[2 * j],     t4y, Qe);
            Po = fmaf(a[2 * j + 1],  t4z, Po);
            Qo = fmaf(bc[2 * j + 1], t4w, Qo);
        }
        float Pp = Pe + Po, Pm = Pe - Po, Qp = Qe + Qo, Qm = Qe - Qo;
        ob[(size_t)v * HH]                        = fast_gelu(Pp + Qp);
        ob[(size_t)(SS / 2 - v) * HH]             = fast_gelu(Pm - Qm);
        ob[(size_t)(SS / 2 + v) * HH]             = fast_gelu(Pm + Qm);
        ob[(size_t)((SS - v) & (SS - 1)) * HH]    = fast_gelu(Pp - Qp);
    }
}

extern "C" void kernel_launch(void* const* d_in, const int* in_sizes, int n_in,
                              void* d_out, int out_size, void* d_ws, size_t ws_size,
                              hipStream_t stream) {
    const float* x   = (const float*)d_in[0];
    const float* w_r = (const float*)d_in[1];
    const float* w_i = (const float*)d_in[2];
    float* out = (float*)d_out;
    float* ws  = (float*)d_ws;

    float* T   = ws;                              // 262144 floats
    float* ABp = ws + 262144;                     // 262144 floats
    float* Xp  = out;                             // 8.39M floats scratch
    float* Wtr = out + (size_t)16 * 1024 * 1024;  // 1M floats scratch
    float* Wti = out + (size_t)17 * 1024 * 1024;  // 1M floats scratch

    hipLaunchKernelGGL(k_pre,   dim3(1024), dim3(256), 0, stream, w_r, w_i, T, Wtr, Wti);
    hipLaunchKernelGGL(k_dft,   dim3(DNC, BB), dim3(256), 0, stream, x, T, Xp);
    hipLaunchKernelGGL(k_mix,   dim3(MM, BB, 2), dim3(256), 0, stream, Xp, Wtr, Wti, ABp);
    hipLaunchKernelGGL(k_synth, dim3(SNC, BB), dim3(256), 0, stream, ABp, T, out);
}

// Round 11
// 123.413 us; speedup vs baseline: 1.2518x; 1.2518x over previous
//
#include <hip/hip_runtime.h>
#include <math.h>

#define BB 16
#define SS 8192
#define HH 256
#define MM 16
#define DNC 64           // k_dft chunks: s-split of [0, 8192)
#define DL 128           // s-rows per chunk
#define SCH 16           // v per k_synth block
#define SNC 129          // k_synth chunks: 128 full + 1 edge
#define QOFF (BB * MM * 2 * HH)   // 131072: ABp h-half stride

// ws layout (floats): T [8192][32] at 0 (262144), ABp [2][BB][MM][2][HH] at
// 262144 (262144 floats).  Total 2 MB.
// d_out scratch: Xp [BB][DNC][MM][2][HH] (8.39M floats, 33.5 MB) at 0, Wt_r at
// 16M floats, Wt_i at 17M floats — all consumed before k_synth overwrites.

// Fused setup: blocks 0..511 build twiddle table T[s][2k]=cos(2pi k s/SS),
// [2k+1]=sin (full s<8192); blocks 512..1023 transpose W
// (Wt[m][h][k'] = w[h][k'][m]) via padded LDS.
__global__ __launch_bounds__(256) void k_pre(const float* __restrict__ wr,
                                             const float* __restrict__ wi,
                                             float* __restrict__ T,
                                             float* __restrict__ Wtr,
                                             float* __restrict__ Wti) {
    const int t = threadIdx.x;
    if (blockIdx.x < 512) {
        int idx = blockIdx.x * 256 + t;     // 0 .. 131071
        int s = idx >> 4, k = idx & 15;
        int r = (k * s) & (SS - 1);         // exact angle reduction
        float th = (float)r * (6.28318530717958647692f / (float)SS);
        float sn, cn;
        sincosf(th, &sn, &cn);
        T[s * 32 + 2 * k]     = cn;
        T[s * 32 + 2 * k + 1] = sn;
    } else {
        __shared__ float lds[4096 + 256];
        int bid = blockIdx.x - 512;         // 0..511
        int h = bid & 255, y = bid >> 8;
        const float* src = (y == 0 ? wr : wi) + (size_t)h * 4096;
        float* dst = (y == 0 ? Wtr : Wti);
#pragma unroll
        for (int j = 0; j < 16; j++) {
            int i = j * 256 + t;
            lds[i + (i >> 4)] = src[i];
        }
        __syncthreads();
#pragma unroll
        for (int m = 0; m < 16; m++) {
            int i = t * 16 + m;
            dst[(size_t)m * (HH * HH) + (size_t)h * HH + t] = lds[i + (i >> 4)];
        }
    }
}

// Branchless exact-GELU via A&S 7.1.26 erf (|err| ~ 1.5e-7).
__device__ __forceinline__ float fast_gelu(float y) {
    float x  = fabsf(y) * 0.70710678118654752f;
    float t  = __builtin_amdgcn_rcpf(fmaf(0.3275911f, x, 1.0f));
    float e  = __expf(-x * x);
    float p  = fmaf(fmaf(fmaf(fmaf(1.061405429f, t, -1.453152027f), t,
                   1.421413741f), t, -0.284496736f), t, 0.254829592f) * t;
    float erfabs = fmaf(-p, e, 1.0f);
    return fmaf(0.5f * fabsf(y), erfabs, 0.5f * y);
}

// Stage 1: pruned forward DFT.  Single contiguous x stream per block (lane t
// owns h=t, scalar loads, 1 KB/block-row).  Twiddle float4 loads have
// wave-uniform addresses (blockIdx/loop-index only) -> hipcc scalar loads
// (s_load_dwordx4, SGPR-resident, no VGPR/LDS/VMEM-vector cost).
// Hand software-pipeline: x-loads for group i+4 issue BEFORE the 128 FMAs of
// group i (register-dependency counted; loads stay in flight across compute).
// cs[k] = sum_s x*cos(2pi k s/S), sn[k] = sum_s x*sin;  X = cs - i*sn.
__global__ __launch_bounds__(256) void k_dft(const float* __restrict__ x,
                                             const float* __restrict__ T,
                                             float* __restrict__ Xp) {
    const int c = blockIdx.x, b = blockIdx.y, t = threadIdx.x;
    const int s0 = c * DL;
    const float* xp = x + ((size_t)b * SS + s0) * HH + t;
    const float* tw = T + (size_t)s0 * 32;

    float cs[MM], sn[MM];
#pragma unroll
    for (int k = 0; k < MM; k++) { cs[k] = 0.f; sn[k] = 0.f; }

    float xv[4], xn[4];
#pragma unroll
    for (int q = 0; q < 4; q++) xv[q] = xp[(size_t)q * HH];

    auto compute4 = [&](int i, const float* xq) {
#pragma unroll
        for (int q = 0; q < 4; q++) {
            const float4* t4 = (const float4*)(tw + (size_t)(i + q) * 32);
            float xval = xq[q];
#pragma unroll
            for (int j = 0; j < 8; j++) {
                float4 tt = t4[j];               // uniform addr -> s_load
                cs[2 * j]     = fmaf(tt.x, xval, cs[2 * j]);
                sn[2 * j]     = fmaf(tt.y, xval, sn[2 * j]);
                cs[2 * j + 1] = fmaf(tt.z, xval, cs[2 * j + 1]);
                sn[2 * j + 1] = fmaf(tt.w, xval, sn[2 * j + 1]);
            }
        }
    };

#pragma unroll 2
    for (int i = 0; i < DL - 4; i += 4) {
#pragma unroll
        for (int q = 0; q < 4; q++)              // prefetch group i+4
            xn[q] = xp[(size_t)(i + 4 + q) * HH];
        compute4(i, xv);                         // consume group i
#pragma unroll
        for (int q = 0; q < 4; q++) xv[q] = xn[q];
    }
    compute4(DL - 4, xv);                        // tail group

    size_t base = ((size_t)(b * DNC + c) * MM) * (2 * HH) + t;
#pragma unroll
    for (int k = 0; k < MM; k++) {
        Xp[base + (size_t)k * (2 * HH)]      = cs[k];
        Xp[base + (size_t)k * (2 * HH) + HH] = sn[k];
    }
}

// Stage 2 (fused reduce+mix, h-split by 2): block (m, b, q) handles h-half
// [q*128, q*128+128).  Phase A: sum Xp over 64 partials (two p-halves across
// thread groups, LDS-combined).  Phase B: partial O[k'] over this h-half:
// X = cs - i*sn;  O[k'] = sum_h X[h]*(wr+i*wi)[h,k',m];
// ABp[q] = scale*Re(O), ABp[q]+HH = -scale*Im(O); k_synth sums the 2 halves.
__global__ __launch_bounds__(256) void k_mix(const float* __restrict__ Xp,
                                             const float* __restrict__ Wtr,
                                             const float* __restrict__ Wti,
                                             float* __restrict__ ABp) {
    const int m = blockIdx.x, b = blockIdx.y, q = blockIdx.z, t = threadIdx.x;
    const int h0 = q * 128;
    __shared__ float tmp[2][2][128];
    __shared__ float xr_s[128], xs_s[128];

    {   // phase A: hh = t&127, p-half = t>>7 (32 p's each)
        int hh = t & 127, ph = t >> 7;
        float s0 = 0.f, s1 = 0.f;
        size_t base = (((size_t)b * DNC + ph * 32) * MM + m) * (2 * HH) + h0 + hh;
        const size_t ps = (size_t)MM * 2 * HH;
#pragma unroll 4
        for (int p = 0; p < 32; p++) {
            s0 += Xp[base + (size_t)p * ps];
            s1 += Xp[base + (size_t)p * ps + HH];
        }
        tmp[ph][0][hh] = s0;
        tmp[ph][1][hh] = s1;
        __syncthreads();
        if (t < 128) {
            xr_s[t] = tmp[0][0][t] + tmp[1][0][t];
            xs_s[t] = tmp[0][1][t] + tmp[1][1][t];
        }
        __syncthreads();
    }

    // phase B: t = k', loop over this h-half
    const float* wr_m = Wtr + (size_t)m * (HH * HH) + (size_t)h0 * HH;
    const float* wi_m = Wti + (size_t)m * (HH * HH) + (size_t)h0 * HH;
    float re = 0.f, im = 0.f;
#pragma unroll 8
    for (int hh = 0; hh < 128; hh++) {
        float a  = wr_m[(size_t)hh * HH + t];   // lane-contiguous, 1KB/wave
        float bw = wi_m[(size_t)hh * HH + t];
        float xr = xr_s[hh];                    // LDS broadcast
        float xs = xs_s[hh];
        re = fmaf(xr, a, re);  re = fmaf(xs, bw, re);
        im = fmaf(xr, bw, im); im = fmaf(-xs, a, im);
    }
    float scale = (m == 0 ? 1.f : 2.f) / (float)SS;
    size_t o = (size_t)q * QOFF + (((size_t)b * MM + m) * 2) * HH + t;
    ABp[o]      = scale * re;
    ABp[o + HH] = -scale * im;
}

// Stage 3: folded synthesis + GELU.  4 outputs per table row:
// y[v]=Pp+Qp, y[4096-v]=Pm-Qm, y[4096+v]=Pm+Qm, y[8192-v]=Pp-Qp
__global__ __launch_bounds__(256) void k_synth(const float* __restrict__ ABp,
                                               const float* __restrict__ T,
                                               float* __restrict__ out) {
    const int c = blockIdx.x, b = blockIdx.y, h = threadIdx.x;
    float a[MM], bc[MM];
#pragma unroll
    for (int k = 0; k < MM; k++) {
        size_t o = (((size_t)b * MM + k) * 2) * HH + h;
        a[k]  = ABp[o]      + ABp[o + QOFF];
        bc[k] = ABp[o + HH] + ABp[o + HH + QOFF];
    }
    const int nv = (c == SNC - 1) ? 1 : SCH;
    const int v0 = c * SCH;
    float* ob = out + (size_t)b * SS * HH + h;

#pragma unroll 2
    for (int i = 0; i < nv; i++) {
        int v = v0 + i;
        const float4* tw4 = (const float4*)(T + (size_t)v * 32);
        float Pe = 0.f, Po = 0.f, Qe = 0.f, Qo = 0.f;
#pragma unroll
        for (int j = 0; j < 8; j++) {
            float4 t = tw4[j];
            Pe = fmaf(a[2 * j],      t.x, Pe);
            Qe = fmaf(bc[2 * j],     t.y, Qe);
            Po = fmaf(a[2 * j + 1],  t.z, Po);
            Qo = fmaf(bc[2 * j + 1], t.w, Qo);
        }
        float Pp = Pe + Po, Pm = Pe - Po, Qp = Qe + Qo, Qm = Qe - Qo;
        ob[(size_t)v * HH]                        = fast_gelu(Pp + Qp);
        ob[(size_t)(SS / 2 - v) * HH]             = fast_gelu(Pm - Qm);
        ob[(size_t)(SS / 2 + v) * HH]             = fast_gelu(Pm + Qm);
        ob[(size_t)((SS - v) & (SS - 1)) * HH]    = fast_gelu(Pp - Qp);
    }
}

extern "C" void kernel_launch(void* const* d_in, const int* in_sizes, int n_in,
                              void* d_out, int out_size, void* d_ws, size_t ws_size,
                              hipStream_t stream) {
    const float* x   = (const float*)d_in[0];
    const float* w_r = (const float*)d_in[1];
    const float* w_i = (const float*)d_in[2];
    float* out = (float*)d_out;
    float* ws  = (float*)d_ws;

    float* T   = ws;                              // 262144 floats
    float* ABp = ws + 262144;                     // 262144 floats
    float* Xp  = out;                             // 8.39M floats scratch
    float* Wtr = out + (size_t)16 * 1024 * 1024;  // 1M floats scratch
    float* Wti = out + (size_t)17 * 1024 * 1024;  // 1M floats scratch

    hipLaunchKernelGGL(k_pre,   dim3(1024), dim3(256), 0, stream, w_r, w_i, T, Wtr, Wti);
    hipLaunchKernelGGL(k_dft,   dim3(DNC, BB), dim3(256), 0, stream, x, T, Xp);
    hipLaunchKernelGGL(k_mix,   dim3(MM, BB, 2), dim3(256), 0, stream, Xp, Wtr, Wti, ABp);
    hipLaunchKernelGGL(k_synth, dim3(SNC, BB), dim3(256), 0, stream, ABp, T, out);
}